// Round 5
// baseline (284.356 us; speedup 1.0000x reference)
//
#include <hip/hip_runtime.h>
#include <hip/hip_bf16.h>
#include <cstdint>
#include <cstddef>

using bf16x8 = __attribute__((ext_vector_type(8))) short;
using f32x4  = __attribute__((ext_vector_type(4))) float;

#define GAS __attribute__((address_space(1)))
#define LAS __attribute__((address_space(3)))

static constexpr int Tdim = 4096;
static constexpr int Ddim = 2048;
static constexpr int N1   = 6144;   // 3*Ddim

__device__ __forceinline__ unsigned short f32_to_bf16(float f) {
    union { float f; unsigned u; } v; v.f = f;
    return (unsigned short)((v.u + 0x7FFFu + ((v.u >> 16) & 1u)) >> 16);
}
__device__ __forceinline__ float bflo(unsigned u){ union{unsigned x;float f;}v; v.x = u << 16;        return v.f; }
__device__ __forceinline__ float bfhi(unsigned u){ union{unsigned x;float f;}v; v.x = u & 0xFFFF0000u; return v.f; }

// ---------------- fused f32 -> bf16 conversion for x, Wq, Wk, Wv ----------------
__global__ __launch_bounds__(256) void cvt_all(const float* __restrict__ x,
                                               const float* __restrict__ Wq,
                                               const float* __restrict__ Wk,
                                               const float* __restrict__ Wv,
                                               unsigned short* __restrict__ xb,
                                               unsigned short* __restrict__ Wb) {
    constexpr int NX = (Tdim * Ddim) / 4;
    constexpr int NWm = (Ddim * Ddim) / 4;
    const int i0 = blockIdx.x * blockDim.x + threadIdx.x;
    const int stride = gridDim.x * blockDim.x;
    for (int i = i0; i < NX + 3 * NWm; i += stride) {
        const float* s; unsigned short* d; int j;
        if (i < NX)            { s = x;  d = xb;                            j = i; }
        else if (i < NX+NWm)   { s = Wq; d = Wb;                            j = i - NX; }
        else if (i < NX+2*NWm) { s = Wk; d = Wb + (size_t)Ddim*Ddim;        j = i - NX - NWm; }
        else                   { s = Wv; d = Wb + 2*(size_t)Ddim*Ddim;      j = i - NX - 2*NWm; }
        float4 f = ((const float4*)s)[j];
        ushort4 o;
        o.x = f32_to_bf16(f.x); o.y = f32_to_bf16(f.y);
        o.z = f32_to_bf16(f.z); o.w = f32_to_bf16(f.w);
        ((ushort4*)d)[j] = o;
    }
}

__device__ __forceinline__ void gload16(const void* g, void* l) {
    __builtin_amdgcn_global_load_lds((GAS void*)g, (LAS void*)l, 16, 0, 0);
}

// T2 swizzle for 64B-stride rows (involution on byte bits [5:4]); maps 16
// consecutive rows x 4 slots onto 8 bank-groups x 2 lanes = conflict-free
// (2-way is free). Verified 0 conflicts in R2-R4.
__device__ __forceinline__ int swz(int r) { return ((r >> 1) & 3) << 4; }

// ================= k1 pipeline: 256x256, 8 waves (2M x 4N), wave-tile 128x64,
// BK=32, 4-deep ring (4 x 32KB), stage-ahead-3, one counted vmcnt(8)/tile =====
static constexpr int SLOT = 32768;               // A 16KB | B 16KB per K-tile
static constexpr int LDS_256 = 4 * SLOT;         // 131072

__device__ __forceinline__ void pipe256(const unsigned short* __restrict__ Ag, int lda,
                                        const unsigned short* __restrict__ Bg, int ldb,
                                        int row0, int col0, int nt,
                                        char* lds, f32x4 acc[8][4]) {
    const int tid = threadIdx.x, wave = tid >> 6, lane = tid & 63;
    const int wr = wave >> 2, wc = wave & 3;     // wave-tile: rows wr*128, cols wc*64

    // staging: 4 gangs/tile (A rows 0-127, A rows 128-255, B 0-127, B 128-255),
    // each gang = 512 thr x 16B = 8KB, LDS-linear; global src pre-swizzled.
    const int gr = tid >> 2;                     // 0..127 row within gang
    const int gc = (tid & 3) << 4;               // byte col 0..48
    const char* sA[2]; const char* sB[2];
    #pragma unroll
    for (int g = 0; g < 2; ++g) {
        int r = g * 128 + gr;
        sA[g] = (const char*)Ag + (size_t)(row0 + r) * (size_t)(lda * 2) + (gc ^ swz(r));
        sB[g] = (const char*)Bg + (size_t)(col0 + r) * (size_t)(ldb * 2) + (gc ^ swz(r));
    }
    const int lw = (tid >> 6) * 1024;            // wave-uniform base within gang region
    // wave-uniform LDS gang bases: A-g at g*8192, B-g at 16384 + g*8192

    const int fr = lane & 15, cB = (lane >> 4) << 4;
    int offA[8], offB[4];
    #pragma unroll
    for (int m = 0; m < 8; ++m) { int r = wr*128 + m*16 + fr; offA[m] = r*64 + (cB ^ swz(r)); }
    #pragma unroll
    for (int n = 0; n < 4; ++n) { int r = wc*64  + n*16 + fr; offB[n] = 16384 + r*64 + (cB ^ swz(r)); }

    #pragma unroll
    for (int m = 0; m < 8; ++m)
        #pragma unroll
        for (int n = 0; n < 4; ++n)
            #pragma unroll
            for (int q = 0; q < 4; ++q) acc[m][n][q] = 0.f;

    // prologue: stage tiles 0,1,2 (12 gangs); the loop's first vmcnt(8) drains tile 0.
    #pragma unroll
    for (int tt = 0; tt < 3; ++tt) {
        char* dst = lds + tt * SLOT;
        const size_t ko = (size_t)tt * 64;       // BK=32 -> 64B per tile along K
        gload16(sA[0] + ko, dst + lw);
        gload16(sA[1] + ko, dst + 8192 + lw);
        gload16(sB[0] + ko, dst + 16384 + lw);
        gload16(sB[1] + ko, dst + 24576 + lw);
    }

    for (int t = 0; t < nt; ++t) {
        const char* buf = lds + (t & 3) * SLOT;
        char* dst = lds + ((t + 3) & 3) * SLOT;  // slot of tile t-1: free once all
        const bool st = (t + 3 < nt);            // waves pass this tile's P1 barrier
        const size_t ko = (size_t)(t + 3) * 64;
        bf16x8 a[4], b[4];

        // ---- P1: drain tile t only (leave t+1,t+2 = 8 in flight) ----
        if (t + 3 <= nt)      asm volatile("s_waitcnt vmcnt(8)" ::: "memory");
        else if (t + 2 == nt) asm volatile("s_waitcnt vmcnt(4)" ::: "memory");
        else                  asm volatile("s_waitcnt vmcnt(0)" ::: "memory");
        __builtin_amdgcn_s_barrier();
        __builtin_amdgcn_sched_barrier(0);
        #pragma unroll
        for (int m = 0; m < 4; ++m) a[m] = *(const bf16x8*)(buf + offA[m]);
        #pragma unroll
        for (int n = 0; n < 4; ++n) b[n] = *(const bf16x8*)(buf + offB[n]);
        if (st) { gload16(sA[0] + ko, dst + lw); gload16(sA[1] + ko, dst + 8192 + lw); }
        __builtin_amdgcn_s_setprio(1);
        #pragma unroll
        for (int m = 0; m < 4; ++m)
            #pragma unroll
            for (int n = 0; n < 4; ++n)
                acc[m][n] = __builtin_amdgcn_mfma_f32_16x16x32_bf16(a[m], b[n], acc[m][n], 0, 0, 0);
        __builtin_amdgcn_s_setprio(0);
        __builtin_amdgcn_sched_barrier(0);

        // ---- P2: rows 64-127 of wave-tile (reuse b) ----
        __builtin_amdgcn_s_barrier();
        __builtin_amdgcn_sched_barrier(0);
        #pragma unroll
        for (int m = 0; m < 4; ++m) a[m] = *(const bf16x8*)(buf + offA[4 + m]);
        if (st) { gload16(sB[0] + ko, dst + 16384 + lw); gload16(sB[1] + ko, dst + 24576 + lw); }
        __builtin_amdgcn_s_setprio(1);
        #pragma unroll
        for (int m = 0; m < 4; ++m)
            #pragma unroll
            for (int n = 0; n < 4; ++n)
                acc[4 + m][n] = __builtin_amdgcn_mfma_f32_16x16x32_bf16(a[m], b[n], acc[4 + m][n], 0, 0, 0);
        __builtin_amdgcn_s_setprio(0);
        __builtin_amdgcn_sched_barrier(0);
    }
}

// ---------------- K1: fused QKV projection + sigmoid epilogue (256x256, 8 waves) ----------------
__global__ __launch_bounds__(512, 2) void k1_proj(const unsigned short* __restrict__ xb,
                                                  const unsigned short* __restrict__ Wb,
                                                  unsigned short* __restrict__ qkv) {
    extern __shared__ __align__(16) char lds[];
    const int s = (blockIdx.x & 7) * 48 + (blockIdx.x >> 3);  // XCD swizzle (384 = 8*48)
    const int bi = s / 24, bj = s % 24;
    f32x4 acc[8][4];
    pipe256(xb, Ddim, Wb, Ddim, bi * 256, bj * 256, Ddim / 32, lds, acc);
    const int lane = threadIdx.x & 63, wave = threadIdx.x >> 6;
    const int wr = wave >> 2, wc = wave & 3;
    const int er = (lane >> 4) * 4, ec = lane & 15;
    #pragma unroll
    for (int n = 0; n < 4; ++n) {
        const int c = bj*256 + wc*64 + n*16 + ec;
        const bool isQK = (c < 2*Ddim);
        const int ihalf = (c & (Ddim-1)) >> 1;
        float theta = 0.0f;
        if (isQK && ihalf < 2) theta = powf(10000.0f, -2.0f*(float)ihalf);
        #pragma unroll
        for (int m = 0; m < 8; ++m) {
            #pragma unroll
            for (int jj = 0; jj < 4; ++jj) {
                const int t = bi*256 + wr*128 + m*16 + er + jj;
                float v = acc[m][n][jj];
                float ov;
                if (isQK) {
                    float cs = 1.0f;  // exact for ihalf>=2 (ang<=4e-13 -> cos+sin==1.0f)
                    if (ihalf < 2) { float ang = (float)t * theta; cs = cosf(ang) + sinf(ang); }
                    float z = v * cs * (1.0f/2048.0f);
                    ov = 1.0f / (1.0f + expf(-z));
                } else {
                    ov = v;
                }
                qkv[(size_t)t * N1 + c] = f32_to_bf16(ov);
            }
        }
    }
}

// ================= 128-tile pipeline (k2/k3, proven R3 version) =================
template<int TBN, int NW>
__device__ __forceinline__ void pipe_gemm(const unsigned short* __restrict__ Ag, int lda,
                                          const unsigned short* __restrict__ Bg, int ldb,
                                          int row0, int col0, int nt,
                                          char* lds, f32x4 acc[4][4]) {
    constexpr int WCOL   = NW / 2;
    constexpr int ISSUES = (128 + TBN) / (NW * 16);
    constexpr int BUF    = (128 + TBN) * 64;
    const int tid = threadIdx.x, wave = tid >> 6, lane = tid & 63;
    const int wr = wave / WCOL, wc = wave % WCOL;

    const char* gp[ISSUES]; int lo[ISSUES];
    #pragma unroll
    for (int i = 0; i < ISSUES; ++i) {
        int o = i * (NW * 1024) + wave * 1024 + (lane << 4);
        lo[i] = i * (NW * 1024) + wave * 1024;
        if (o < 128 * 64) {
            int r = o >> 6, cp = o & 63;
            gp[i] = (const char*)Ag + (size_t)(row0 + r) * (size_t)lda * 2 + (cp ^ swz(r));
        } else {
            int o2 = o - 128 * 64; int r = o2 >> 6, cp = o2 & 63;
            gp[i] = (const char*)Bg + (size_t)(col0 + r) * (size_t)ldb * 2 + (cp ^ swz(r));
        }
    }
    const int fr = lane & 15, fkB = (lane >> 4) << 4;
    int offA[4], offB[4];
    #pragma unroll
    for (int m = 0; m < 4; ++m) { int r = wr*64 + m*16 + fr; offA[m] = r*64 + (fkB ^ swz(r)); }
    #pragma unroll
    for (int n = 0; n < 4; ++n) { int r = wc*64 + n*16 + fr; offB[n] = 128*64 + r*64 + (fkB ^ swz(r)); }

    #pragma unroll
    for (int m = 0; m < 4; ++m)
        #pragma unroll
        for (int n = 0; n < 4; ++n)
            #pragma unroll
            for (int q = 0; q < 4; ++q) acc[m][n][q] = 0.0f;

    #pragma unroll
    for (int tt = 0; tt < 2; ++tt) {
        char* dst = lds + tt * BUF;
        #pragma unroll
        for (int i = 0; i < ISSUES; ++i) gload16(gp[i] + (size_t)tt * 64, dst + lo[i]);
    }
    asm volatile("s_waitcnt vmcnt(%0)" :: "n"(ISSUES) : "memory");
    __builtin_amdgcn_s_barrier();
    __builtin_amdgcn_sched_barrier(0);

    int cur = 0, stg = 2 * BUF;
    for (int t = 0; t < nt; ++t) {
        const char* buf = lds + cur;
        bf16x8 af[4], bq[4];
        #pragma unroll
        for (int m = 0; m < 4; ++m) af[m] = *(const bf16x8*)(buf + offA[m]);
        #pragma unroll
        for (int n = 0; n < 4; ++n) bq[n] = *(const bf16x8*)(buf + offB[n]);
        if (t + 2 < nt) {
            char* dst = lds + stg;
            const size_t ko = (size_t)(t + 2) * 64;
            #pragma unroll
            for (int i = 0; i < ISSUES; ++i) gload16(gp[i] + ko, dst + lo[i]);
        }
        __builtin_amdgcn_s_setprio(1);
        #pragma unroll
        for (int m = 0; m < 4; ++m)
            #pragma unroll
            for (int n = 0; n < 4; ++n)
                acc[m][n] = __builtin_amdgcn_mfma_f32_16x16x32_bf16(af[m], bq[n], acc[m][n], 0, 0, 0);
        __builtin_amdgcn_s_setprio(0);
        __builtin_amdgcn_sched_barrier(0);
        if (t + 1 < nt) {
            if (t + 3 <= nt) asm volatile("s_waitcnt vmcnt(%0)" :: "n"(ISSUES) : "memory");
            else             asm volatile("s_waitcnt vmcnt(0)" ::: "memory");
            __builtin_amdgcn_s_barrier();
            __builtin_amdgcn_sched_barrier(0);
        }
        cur = (cur == 2*BUF) ? 0 : cur + BUF;
        stg = (stg == 2*BUF) ? 0 : stg + BUF;
    }
}

static constexpr int LDS_K2 = 3 * (128 + 128) * 64;  // 49152 B

// ---------------- K1b: transpose V -> vT [2048][4096] ----------------
__global__ __launch_bounds__(256) void k1b_trans(const unsigned short* __restrict__ qkv,
                                                 unsigned short* __restrict__ vT) {
    __shared__ unsigned short tile[64][65];
    const int tc = blockIdx.x, tr = blockIdx.y;
    const int x = threadIdx.x & 63, y0 = threadIdx.x >> 6;
    #pragma unroll
    for (int r = 0; r < 64; r += 4) {
        const int row = r + y0;
        tile[row][x] = qkv[(size_t)(tr*64 + row) * N1 + 2*Ddim + tc*64 + x];
    }
    __syncthreads();
    #pragma unroll
    for (int r = 0; r < 64; r += 4) {
        const int row = r + y0;
        vT[(size_t)(tc*64 + row) * Tdim + tr*64 + x] = tile[x][row];
    }
}

// ---------------- K2: A = query @ key^T, lower-tri 128x128 blocks (528) ----------------
__global__ __launch_bounds__(256, 3) void k2_qk(const unsigned short* __restrict__ qkv,
                                                unsigned short* __restrict__ Am) {
    extern __shared__ __align__(16) char lds[];
    const int p = (blockIdx.x & 7) * 66 + (blockIdx.x >> 3);  // XCD swizzle (528 = 8*66)
    int bi = (int)((sqrtf(8.0f*(float)p + 1.0f) - 1.0f) * 0.5f);
    while ((bi+1)*(bi+2)/2 <= p) ++bi;
    while (bi*(bi+1)/2 > p) --bi;
    const int bj = p - bi*(bi+1)/2;
    f32x4 acc[4][4];
    pipe_gemm<128, 4>(qkv, N1, qkv + Ddim, N1, bi*128, bj*128, Ddim/32, lds, acc);
    const int lane = threadIdx.x & 63, wave = threadIdx.x >> 6;
    const int wr = wave >> 1, wc = wave & 1;
    const int er = (lane >> 4) * 4, ec = lane & 15;
    #pragma unroll
    for (int n = 0; n < 4; ++n) {
        const int s = bj*128 + wc*64 + n*16 + ec;
        #pragma unroll
        for (int m = 0; m < 4; ++m)
            #pragma unroll
            for (int jj = 0; jj < 4; ++jj) {
                const int t = bi*128 + wr*64 + m*16 + er + jj;
                float v = (s <= t) ? acc[m][n][jj] : 0.0f;
                Am[(size_t)t * Tdim + s] = f32_to_bf16(v);
            }
    }
}

// ---------------- K2b: rden[t] = 1 / sum_{s<=t} A[t][s] ----------------
__global__ __launch_bounds__(256) void k2b_den(const unsigned short* __restrict__ Am,
                                               float* __restrict__ rden) {
    const int t = blockIdx.x;
    const int lim = ((t >> 7) + 1) << 7;
    const unsigned short* row = Am + (size_t)t * Tdim;
    float s = 0.0f;
    for (int idx = threadIdx.x * 8; idx < lim; idx += 2048) {
        uint4 u = *(const uint4*)(row + idx);
        s += bflo(u.x) + bfhi(u.x) + bflo(u.y) + bfhi(u.y)
           + bflo(u.z) + bfhi(u.z) + bflo(u.w) + bfhi(u.w);
    }
    #pragma unroll
    for (int off = 32; off > 0; off >>= 1) s += __shfl_down(s, off, 64);
    __shared__ float red[4];
    const int lane = threadIdx.x & 63, wave = threadIdx.x >> 6;
    if (lane == 0) red[wave] = s;
    __syncthreads();
    if (threadIdx.x == 0) rden[t] = 1.0f / (red[0] + red[1] + red[2] + red[3]);
}

// ---------------- K3: Y = (A @ V) * rden, ragged K, 128x128 blocks ----------------
__global__ __launch_bounds__(256, 3) void k3_out(const unsigned short* __restrict__ Am,
                                                 const unsigned short* __restrict__ vT,
                                                 const float* __restrict__ rden,
                                                 float* __restrict__ out) {
    extern __shared__ __align__(16) char lds[];
    const int bi = blockIdx.y, bj = blockIdx.x;
    f32x4 acc[4][4];
    pipe_gemm<128, 4>(Am, Tdim, vT, Tdim, bi*128, bj*128, (bi + 1) * 4, lds, acc);
    const int lane = threadIdx.x & 63, wave = threadIdx.x >> 6;
    const int wr = wave >> 1, wc = wave & 1;
    const int er = (lane >> 4) * 4, ec = lane & 15;
    #pragma unroll
    for (int n = 0; n < 4; ++n) {
        const int c = bj*128 + wc*64 + n*16 + ec;
        #pragma unroll
        for (int m = 0; m < 4; ++m)
            #pragma unroll
            for (int jj = 0; jj < 4; ++jj) {
                const int t = bi*128 + wr*64 + m*16 + er + jj;
                out[(size_t)t * Ddim + c] = acc[m][n][jj] * rden[t];
            }
    }
}

// ---------------- launch ----------------
extern "C" void kernel_launch(void* const* d_in, const int* in_sizes, int n_in,
                              void* d_out, int out_size, void* d_ws, size_t ws_size,
                              hipStream_t stream) {
    const float* x  = (const float*)d_in[0];
    const float* Wq = (const float*)d_in[1];
    const float* Wk = (const float*)d_in[2];
    const float* Wv = (const float*)d_in[3];
    char* ws = (char*)d_ws;
    unsigned short* xb   = (unsigned short*)(ws + 0);
    unsigned short* Wb   = (unsigned short*)(ws + (size_t)16777216);
    unsigned short* qkv  = (unsigned short*)(ws + (size_t)41943040);
    unsigned short* vT   = (unsigned short*)(ws + (size_t)92274688);
    unsigned short* Am   = (unsigned short*)(ws + 0);
    float*          rden = (float*)(ws + (size_t)109051904);
    float* out = (float*)d_out;

    (void)hipFuncSetAttribute((const void*)k1_proj, hipFuncAttributeMaxDynamicSharedMemorySize, LDS_256);

    cvt_all <<<2048, 256, 0, stream>>>(x, Wq, Wk, Wv, xb, Wb);
    k1_proj <<<dim3(384), 512, LDS_256, stream>>>(xb, Wb, qkv);
    k1b_trans<<<dim3(Ddim/64, Tdim/64), 256, 0, stream>>>(qkv, vT);
    k2_qk   <<<dim3(528), 256, LDS_K2, stream>>>(qkv, Am);
    k2b_den <<<dim3(Tdim), 256, 0, stream>>>(Am, rden);
    k3_out  <<<dim3(Ddim/128, Tdim/128), 256, LDS_K2, stream>>>(Am, vT, rden, out);
}

// Round 6
// 267.186 us; speedup vs baseline: 1.0643x; 1.0643x over previous
//
#include <hip/hip_runtime.h>
#include <hip/hip_bf16.h>
#include <cstdint>
#include <cstddef>

using bf16x8 = __attribute__((ext_vector_type(8))) short;
using f32x4  = __attribute__((ext_vector_type(4))) float;

#define GAS __attribute__((address_space(1)))
#define LAS __attribute__((address_space(3)))

static constexpr int Tdim = 4096;
static constexpr int Ddim = 2048;
static constexpr int N1   = 6144;   // 3*Ddim

__device__ __forceinline__ unsigned short f32_to_bf16(float f) {
    union { float f; unsigned u; } v; v.f = f;
    return (unsigned short)((v.u + 0x7FFFu + ((v.u >> 16) & 1u)) >> 16);
}
__device__ __forceinline__ float bflo(unsigned u){ union{unsigned x;float f;}v; v.x = u << 16;        return v.f; }
__device__ __forceinline__ float bfhi(unsigned u){ union{unsigned x;float f;}v; v.x = u & 0xFFFF0000u; return v.f; }

// ---------------- fused f32 -> bf16 conversion for x, Wq, Wk, Wv ----------------
__global__ __launch_bounds__(256) void cvt_all(const float* __restrict__ x,
                                               const float* __restrict__ Wq,
                                               const float* __restrict__ Wk,
                                               const float* __restrict__ Wv,
                                               unsigned short* __restrict__ xb,
                                               unsigned short* __restrict__ Wb) {
    constexpr int NX = (Tdim * Ddim) / 4;
    constexpr int NWm = (Ddim * Ddim) / 4;
    const int i0 = blockIdx.x * blockDim.x + threadIdx.x;
    const int stride = gridDim.x * blockDim.x;
    for (int i = i0; i < NX + 3 * NWm; i += stride) {
        const float* s; unsigned short* d; int j;
        if (i < NX)            { s = x;  d = xb;                            j = i; }
        else if (i < NX+NWm)   { s = Wq; d = Wb;                            j = i - NX; }
        else if (i < NX+2*NWm) { s = Wk; d = Wb + (size_t)Ddim*Ddim;        j = i - NX - NWm; }
        else                   { s = Wv; d = Wb + 2*(size_t)Ddim*Ddim;      j = i - NX - 2*NWm; }
        float4 f = ((const float4*)s)[j];
        ushort4 o;
        o.x = f32_to_bf16(f.x); o.y = f32_to_bf16(f.y);
        o.z = f32_to_bf16(f.z); o.w = f32_to_bf16(f.w);
        ((ushort4*)d)[j] = o;
    }
}

__device__ __forceinline__ void gload16(const void* g, void* l) {
    __builtin_amdgcn_global_load_lds((GAS void*)g, (LAS void*)l, 16, 0, 0);
}

// T2 swizzle for 64B-stride rows (involution on byte bits [5:4]): 16 consecutive
// rows x 4 slots -> 8 bank-groups x 2 lanes = conflict-free (verified 0 in R2-R5).
__device__ __forceinline__ int swz(int r) { return ((r >> 1) & 3) << 4; }

// ============ generalized proven 2-phase ring-3 pipeline ============
// C[TBM x TBN] = A[row0..+TBM, K] * B[col0..+TBN, K]^T ; bf16 row-major.
// NW waves in (TBM/(MR*16)) x (TBN/64) grid; wave-tile (MR*16) x 64.
// Ring-3 LDS, stage-ahead-2, counted vmcnt (never 0 mid-loop). Same code
// path as the R3-proven template; only geometry is parameterized.
template<int TBM, int TBN, int NW, int MR>
__device__ __forceinline__ void pipe_gemm(const unsigned short* __restrict__ Ag, int lda,
                                          const unsigned short* __restrict__ Bg, int ldb,
                                          int row0, int col0, int nt,
                                          char* lds, f32x4 acc[MR][4]) {
    constexpr int WCOL   = TBN / 64;
    constexpr int ISSUES = (TBM + TBN) / (NW * 16);
    constexpr int BUF    = (TBM + TBN) * 64;
    const int tid = threadIdx.x, wave = tid >> 6, lane = tid & 63;
    const int wr = wave / WCOL, wc = wave % WCOL;

    // staging: LDS-linear gangs (DMA constraint), global src pre-swizzled (rule 21)
    const char* gp[ISSUES]; int lo[ISSUES];
    #pragma unroll
    for (int i = 0; i < ISSUES; ++i) {
        int o = i * (NW * 1024) + wave * 1024 + (lane << 4);
        lo[i] = i * (NW * 1024) + wave * 1024;
        if (o < TBM * 64) {
            int r = o >> 6, cp = o & 63;
            gp[i] = (const char*)Ag + (size_t)(row0 + r) * (size_t)lda * 2 + (cp ^ swz(r));
        } else {
            int o2 = o - TBM * 64; int r = o2 >> 6, cp = o2 & 63;
            gp[i] = (const char*)Bg + (size_t)(col0 + r) * (size_t)ldb * 2 + (cp ^ swz(r));
        }
    }
    const int fr = lane & 15, fkB = (lane >> 4) << 4;
    int offA[MR], offB[4];
    #pragma unroll
    for (int m = 0; m < MR; ++m) { int r = wr*(MR*16) + m*16 + fr; offA[m] = r*64 + (fkB ^ swz(r)); }
    #pragma unroll
    for (int n = 0; n < 4; ++n)  { int r = wc*64 + n*16 + fr; offB[n] = TBM*64 + r*64 + (fkB ^ swz(r)); }

    #pragma unroll
    for (int m = 0; m < MR; ++m)
        #pragma unroll
        for (int n = 0; n < 4; ++n)
            #pragma unroll
            for (int q = 0; q < 4; ++q) acc[m][n][q] = 0.0f;

    #pragma unroll
    for (int tt = 0; tt < 2; ++tt) {
        char* dst = lds + tt * BUF;
        #pragma unroll
        for (int i = 0; i < ISSUES; ++i) gload16(gp[i] + (size_t)tt * 64, dst + lo[i]);
    }
    asm volatile("s_waitcnt vmcnt(%0)" :: "n"(ISSUES) : "memory");
    __builtin_amdgcn_s_barrier();
    __builtin_amdgcn_sched_barrier(0);

    int cur = 0, stg = 2 * BUF;
    for (int t = 0; t < nt; ++t) {
        const char* buf = lds + cur;
        bf16x8 af[MR], bq[4];
        #pragma unroll
        for (int m = 0; m < MR; ++m) af[m] = *(const bf16x8*)(buf + offA[m]);
        #pragma unroll
        for (int n = 0; n < 4; ++n) bq[n] = *(const bf16x8*)(buf + offB[n]);
        if (t + 2 < nt) {
            char* dst = lds + stg;
            const size_t ko = (size_t)(t + 2) * 64;
            #pragma unroll
            for (int i = 0; i < ISSUES; ++i) gload16(gp[i] + ko, dst + lo[i]);
        }
        __builtin_amdgcn_s_setprio(1);
        #pragma unroll
        for (int m = 0; m < MR; ++m)
            #pragma unroll
            for (int n = 0; n < 4; ++n)
                acc[m][n] = __builtin_amdgcn_mfma_f32_16x16x32_bf16(af[m], bq[n], acc[m][n], 0, 0, 0);
        __builtin_amdgcn_s_setprio(0);
        __builtin_amdgcn_sched_barrier(0);
        if (t + 1 < nt) {
            if (t + 3 <= nt) asm volatile("s_waitcnt vmcnt(%0)" :: "n"(ISSUES) : "memory");
            else             asm volatile("s_waitcnt vmcnt(0)" ::: "memory");
            __builtin_amdgcn_s_barrier();
            __builtin_amdgcn_sched_barrier(0);
        }
        cur = (cur == 2*BUF) ? 0 : cur + BUF;
        stg = (stg == 2*BUF) ? 0 : stg + BUF;
    }
}

static constexpr int LDS_K1 = 3 * (256 + 128) * 64;  // 73728 B -> 2 blocks/CU
static constexpr int LDS_K2 = 3 * (128 + 128) * 64;  // 49152 B -> 3 blocks/CU

// ---------------- K1: fused QKV projection + sigmoid epilogue ----------------
// 256x128 tile, 4 waves, wave-tile 128x64; grid 768 = 3 blocks/CU uniform.
__global__ __launch_bounds__(256, 2) void k1_proj(const unsigned short* __restrict__ xb,
                                                  const unsigned short* __restrict__ Wb,
                                                  unsigned short* __restrict__ qkv) {
    extern __shared__ __align__(16) char lds[];
    const int s = (blockIdx.x & 7) * 96 + (blockIdx.x >> 3);  // XCD swizzle (768 = 8*96)
    const int bi = s / 48, bj = s % 48;
    f32x4 acc[8][4];
    pipe_gemm<256, 128, 4, 8>(xb, Ddim, Wb, Ddim, bi*256, bj*128, Ddim/32, lds, acc);
    const int lane = threadIdx.x & 63, wave = threadIdx.x >> 6;
    const int wr = wave >> 1, wc = wave & 1;
    const int er = (lane >> 4) * 4, ec = lane & 15;
    #pragma unroll
    for (int n = 0; n < 4; ++n) {
        const int c = bj*128 + wc*64 + n*16 + ec;
        const bool isQK = (c < 2*Ddim);
        const int ihalf = (c & (Ddim-1)) >> 1;
        float theta = 0.0f;
        if (isQK && ihalf < 2) theta = powf(10000.0f, -2.0f*(float)ihalf);
        #pragma unroll
        for (int m = 0; m < 8; ++m) {
            #pragma unroll
            for (int jj = 0; jj < 4; ++jj) {
                const int t = bi*256 + wr*128 + m*16 + er + jj;
                float v = acc[m][n][jj];
                float ov;
                if (isQK) {
                    float cs = 1.0f;  // exact for ihalf>=2 (ang<=4e-13 -> cos+sin==1.0f)
                    if (ihalf < 2) { float ang = (float)t * theta; cs = cosf(ang) + sinf(ang); }
                    float z = v * cs * (1.0f/2048.0f);
                    ov = 1.0f / (1.0f + expf(-z));
                } else {
                    ov = v;
                }
                qkv[(size_t)t * N1 + c] = f32_to_bf16(ov);
            }
        }
    }
}

// ---------------- K1b: transpose V -> vT [2048][4096] ----------------
__global__ __launch_bounds__(256) void k1b_trans(const unsigned short* __restrict__ qkv,
                                                 unsigned short* __restrict__ vT) {
    __shared__ unsigned short tile[64][65];
    const int tc = blockIdx.x, tr = blockIdx.y;
    const int x = threadIdx.x & 63, y0 = threadIdx.x >> 6;
    #pragma unroll
    for (int r = 0; r < 64; r += 4) {
        const int row = r + y0;
        tile[row][x] = qkv[(size_t)(tr*64 + row) * N1 + 2*Ddim + tc*64 + x];
    }
    __syncthreads();
    #pragma unroll
    for (int r = 0; r < 64; r += 4) {
        const int row = r + y0;
        vT[(size_t)(tc*64 + row) * Tdim + tr*64 + x] = tile[x][row];
    }
}

// ---------------- K2: A = query @ key^T, lower-tri 128x128 blocks (528) ----------------
__global__ __launch_bounds__(256, 3) void k2_qk(const unsigned short* __restrict__ qkv,
                                                unsigned short* __restrict__ Am) {
    extern __shared__ __align__(16) char lds[];
    const int p = (blockIdx.x & 7) * 66 + (blockIdx.x >> 3);  // XCD swizzle (528 = 8*66)
    int bi = (int)((sqrtf(8.0f*(float)p + 1.0f) - 1.0f) * 0.5f);
    while ((bi+1)*(bi+2)/2 <= p) ++bi;
    while (bi*(bi+1)/2 > p) --bi;
    const int bj = p - bi*(bi+1)/2;
    f32x4 acc[4][4];
    pipe_gemm<128, 128, 4, 4>(qkv, N1, qkv + Ddim, N1, bi*128, bj*128, Ddim/32, lds, acc);
    const int lane = threadIdx.x & 63, wave = threadIdx.x >> 6;
    const int wr = wave >> 1, wc = wave & 1;
    const int er = (lane >> 4) * 4, ec = lane & 15;
    #pragma unroll
    for (int n = 0; n < 4; ++n) {
        const int s = bj*128 + wc*64 + n*16 + ec;
        #pragma unroll
        for (int m = 0; m < 4; ++m)
            #pragma unroll
            for (int jj = 0; jj < 4; ++jj) {
                const int t = bi*128 + wr*64 + m*16 + er + jj;
                float v = (s <= t) ? acc[m][n][jj] : 0.0f;
                Am[(size_t)t * Tdim + s] = f32_to_bf16(v);
            }
    }
}

// ---------------- K2b: rden[t] = 1 / sum_{s<=t} A[t][s] ----------------
__global__ __launch_bounds__(256) void k2b_den(const unsigned short* __restrict__ Am,
                                               float* __restrict__ rden) {
    const int t = blockIdx.x;
    const int lim = ((t >> 7) + 1) << 7;
    const unsigned short* row = Am + (size_t)t * Tdim;
    float s = 0.0f;
    for (int idx = threadIdx.x * 8; idx < lim; idx += 2048) {
        uint4 u = *(const uint4*)(row + idx);
        s += bflo(u.x) + bfhi(u.x) + bflo(u.y) + bfhi(u.y)
           + bflo(u.z) + bfhi(u.z) + bflo(u.w) + bfhi(u.w);
    }
    #pragma unroll
    for (int off = 32; off > 0; off >>= 1) s += __shfl_down(s, off, 64);
    __shared__ float red[4];
    const int lane = threadIdx.x & 63, wave = threadIdx.x >> 6;
    if (lane == 0) red[wave] = s;
    __syncthreads();
    if (threadIdx.x == 0) rden[t] = 1.0f / (red[0] + red[1] + red[2] + red[3]);
}

// ---------------- K3: Y = (A @ V) * rden, ragged K, 128x128 blocks ----------------
// Long/short pairing: bid<256 -> bi = 31-(bid>>4) (long), bid>=256 -> bi = (bid-256)>>4
// (short). bid and bid+256 land on the same CU under round-robin dispatch -> per-CU
// K-work constant (33*4 tiles).
__global__ __launch_bounds__(256, 3) void k3_out(const unsigned short* __restrict__ Am,
                                                 const unsigned short* __restrict__ vT,
                                                 const float* __restrict__ rden,
                                                 float* __restrict__ out) {
    extern __shared__ __align__(16) char lds[];
    const int bid = blockIdx.x;
    const int bi = (bid < 256) ? (31 - (bid >> 4)) : ((bid - 256) >> 4);
    const int bj = bid & 15;
    f32x4 acc[4][4];
    pipe_gemm<128, 128, 4, 4>(Am, Tdim, vT, Tdim, bi*128, bj*128, (bi + 1) * 4, lds, acc);
    const int lane = threadIdx.x & 63, wave = threadIdx.x >> 6;
    const int wr = wave >> 1, wc = wave & 1;
    const int er = (lane >> 4) * 4, ec = lane & 15;
    #pragma unroll
    for (int n = 0; n < 4; ++n) {
        const int c = bj*128 + wc*64 + n*16 + ec;
        #pragma unroll
        for (int m = 0; m < 4; ++m)
            #pragma unroll
            for (int jj = 0; jj < 4; ++jj) {
                const int t = bi*128 + wr*64 + m*16 + er + jj;
                out[(size_t)t * Ddim + c] = acc[m][n][jj] * rden[t];
            }
    }
}

// ---------------- launch ----------------
extern "C" void kernel_launch(void* const* d_in, const int* in_sizes, int n_in,
                              void* d_out, int out_size, void* d_ws, size_t ws_size,
                              hipStream_t stream) {
    const float* x  = (const float*)d_in[0];
    const float* Wq = (const float*)d_in[1];
    const float* Wk = (const float*)d_in[2];
    const float* Wv = (const float*)d_in[3];
    char* ws = (char*)d_ws;
    unsigned short* xb   = (unsigned short*)(ws + 0);
    unsigned short* Wb   = (unsigned short*)(ws + (size_t)16777216);
    unsigned short* qkv  = (unsigned short*)(ws + (size_t)41943040);
    unsigned short* vT   = (unsigned short*)(ws + (size_t)92274688);
    unsigned short* Am   = (unsigned short*)(ws + 0);
    float*          rden = (float*)(ws + (size_t)109051904);
    float* out = (float*)d_out;

    (void)hipFuncSetAttribute((const void*)k1_proj, hipFuncAttributeMaxDynamicSharedMemorySize, LDS_K1);

    cvt_all <<<2048, 256, 0, stream>>>(x, Wq, Wk, Wv, xb, Wb);
    k1_proj <<<dim3(768), 256, LDS_K1, stream>>>(xb, Wb, qkv);
    k1b_trans<<<dim3(Ddim/64, Tdim/64), 256, 0, stream>>>(qkv, vT);
    k2_qk   <<<dim3(528), 256, LDS_K2, stream>>>(qkv, Am);
    k2b_den <<<dim3(Tdim), 256, 0, stream>>>(Am, rden);
    k3_out  <<<dim3(512), 256, LDS_K2, stream>>>(Am, vT, rden, out);
}